// Round 3
// baseline (790.501 us; speedup 1.0000x reference)
//
#include <hip/hip_runtime.h>
#include <math.h>

// LSTMClassifier fused kernel for MI355X (gfx950) — round 2
// B=1024, S=512, I=50, H=64, F1=32, C=2
// grid=256 (1 block/CU), 1024 threads/block, 4 batch/block.
// GEMM role:  thread u owns gate-row jg=u&255, K-slice kp=u>>8 (29 of 116).
//             Weights are 29 NAMED SCALARS -> guaranteed VGPR-resident.
// Cell role:  lane-quad owns one (b,j) cell, one gate per lane; gates are
//             combined in-register via __shfl_xor (no extra barrier).

#define B_TOT  1024
#define S_LEN  512
#define I_DIM  50
#define H_DIM  64
#define G4     256          // 4*H
#define KTOT   114          // I_DIM + H_DIM
#define KPAD   116          // padded to 4*29
#define KPL    29           // K per slice
#define BB     4            // batch per block
#define F1_DIM 32
#define C_DIM  2

__device__ __forceinline__ float fast_rcp(float x) {
    return __builtin_amdgcn_rcpf(x);
}
__device__ __forceinline__ float tanh_fast(float v) {
    return 1.0f - 2.0f * fast_rcp(__expf(2.0f * v) + 1.0f);
}

__global__ __launch_bounds__(1024, 4)
void lstm_fused(const float* __restrict__ x,
                const float* __restrict__ W_ih, const float* __restrict__ W_hh,
                const float* __restrict__ b_ih, const float* __restrict__ b_hh,
                const float* __restrict__ W1,  const float* __restrict__ b1,
                const float* __restrict__ W2,  const float* __restrict__ b2,
                float* __restrict__ out)
{
    __shared__ __align__(16) float act[2][KPAD][BB];   // k<50: x(t); 50..113: h(t); 114/115: 0
    __shared__ float partial[4][BB][G4];               // [kslice][b][gate_row]
    __shared__ float f1buf[BB][F1_DIM];

    const int u  = threadIdx.x;              // 0..1023
    const int jg = u & 255;                  // owned gate-row
    const int kp = u >> 8;                   // K-slice 0..3
    const int k0 = kp * KPL;
    const int b0 = blockIdx.x * BB;

    // ---- 29 weight scalars in registers (one-time load) ----
#define LDW(i) const float w##i = ((k0 + i) < I_DIM) \
        ? W_ih[jg * I_DIM + (k0 + i)] \
        : (((k0 + i) < KTOT) ? W_hh[jg * H_DIM + (k0 + i - I_DIM)] : 0.0f);
    LDW(0)  LDW(1)  LDW(2)  LDW(3)  LDW(4)  LDW(5)  LDW(6)  LDW(7)
    LDW(8)  LDW(9)  LDW(10) LDW(11) LDW(12) LDW(13) LDW(14) LDW(15)
    LDW(16) LDW(17) LDW(18) LDW(19) LDW(20) LDW(21) LDW(22) LDW(23)
    LDW(24) LDW(25) LDW(26) LDW(27) LDW(28)
#undef LDW

    // ---- elementwise role: lane-quad per cell, one gate per lane ----
    const int eg  = u & 3;                   // gate: 0=i 1=f 2=g~ 3=o
    const int eq  = u >> 2;                  // cell 0..255
    const int ebb = eq >> 6;                 // batch 0..3
    const int ejj = eq & 63;                 // hidden unit
    const int erow = eg * H_DIM + ejj;       // row in gate space
    const float ebias = b_ih[erow] + b_hh[erow];
    const float mIn  = (eg == 2) ? 2.0f : 1.0f;   // tanh(s)=2*sigm(2s)-1
    const float mOut = (eg == 2) ? 2.0f : 1.0f;
    const float aOut = (eg == 2) ? -1.0f : 0.0f;
    float c_state = 0.0f;                    // live in eg==0 lanes

    // ---- x-prefetch role: threads 768..967 ----
    const int pv = u - 768;
    const bool is_pref = (pv >= 0) && (pv < BB * I_DIM);
    const int pb = is_pref ? (pv / I_DIM) : 0;
    const int pi = is_pref ? (pv - pb * I_DIM) : 0;

    // ---- init: x(0), h(0)=0, zero pad rows of both buffers ----
    if (is_pref) act[0][pi][pb] = x[(size_t)(b0 + pb) * (S_LEN * I_DIM) + pi];
    if (u < 256) act[0][I_DIM + (u & 63)][u >> 6] = 0.0f;
    if (u < 16)  act[u >> 3][KTOT + ((u >> 2) & 1)][u & 3] = 0.0f;
    __syncthreads();

    // ---- sequential scan ----
    for (int t = 0; t < S_LEN; ++t) {
        const int cur = t & 1, nxt = cur ^ 1;

        // prefetch x(t+1) (latency hides under GEMM)
        float xpre = 0.0f;
        const bool do_pref = is_pref && (t + 1 < S_LEN);
        if (do_pref)
            xpre = x[(size_t)(b0 + pb) * (S_LEN * I_DIM) + (t + 1) * I_DIM + pi];

        // gate GEMM over this thread's K-slice (broadcast LDS reads)
        float a0 = 0.0f, a1 = 0.0f, a2 = 0.0f, a3 = 0.0f;
#define FMA4(i) { const float4 av = *reinterpret_cast<const float4*>(&act[cur][k0 + i][0]); \
                  a0 = fmaf(w##i, av.x, a0); a1 = fmaf(w##i, av.y, a1);                     \
                  a2 = fmaf(w##i, av.z, a2); a3 = fmaf(w##i, av.w, a3); }
        FMA4(0)  FMA4(1)  FMA4(2)  FMA4(3)  FMA4(4)  FMA4(5)  FMA4(6)  FMA4(7)
        FMA4(8)  FMA4(9)  FMA4(10) FMA4(11) FMA4(12) FMA4(13) FMA4(14) FMA4(15)
        FMA4(16) FMA4(17) FMA4(18) FMA4(19) FMA4(20) FMA4(21) FMA4(22) FMA4(23)
        FMA4(24) FMA4(25) FMA4(26) FMA4(27) FMA4(28)
#undef FMA4
        partial[kp][0][jg] = a0;             // consecutive jg -> conflict-free
        partial[kp][1][jg] = a1;
        partial[kp][2][jg] = a2;
        partial[kp][3][jg] = a3;
        if (do_pref) act[nxt][pi][pb] = xpre;
        __syncthreads();

        // per-gate: combine K-slices, activate
        float s = ebias + partial[0][ebb][erow] + partial[1][ebb][erow]
                        + partial[2][ebb][erow] + partial[3][ebb][erow];
        const float v = mOut * fast_rcp(1.0f + __expf(-mIn * s)) + aOut;

        // quad exchange: lane eg==0 collects (i, f, g~, o)
        const float vx1  = __shfl_xor(v, 1);
        const float vx2  = __shfl_xor(v, 2);
        const float vx12 = __shfl_xor(vx1, 2);
        if (eg == 0) {
            // v=i, vx1=f, vx2=g~, vx12=o
            c_state = fmaf(vx1, c_state, v * vx2);
            act[nxt][I_DIM + ejj][ebb] = vx12 * tanh_fast(c_state);
        }
        __syncthreads();
    }

    // ---- classifier head; h_last in act[0][50+j][b] (S_LEN even) ----
    if (u < BB * F1_DIM) {                   // 128 threads
        const int b = u >> 5, f = u & 31;
        float acc = b1[f];
        #pragma unroll
        for (int j = 0; j < H_DIM; ++j)
            acc = fmaf(act[0][I_DIM + j][b], W1[f * H_DIM + j], acc);
        f1buf[b][f] = fmaxf(acc, 0.0f);
    }
    __syncthreads();
    if (u < BB * C_DIM) {                    // 8 threads
        const int b = u >> 1, cl = u & 1;
        float acc = b2[cl];
        #pragma unroll
        for (int f = 0; f < F1_DIM; ++f)
            acc = fmaf(f1buf[b][f], W2[cl * F1_DIM + f], acc);
        out[(size_t)(b0 + b) * C_DIM + cl] = acc;
    }
}

extern "C" void kernel_launch(void* const* d_in, const int* in_sizes, int n_in,
                              void* d_out, int out_size, void* d_ws, size_t ws_size,
                              hipStream_t stream) {
    const float* x   = (const float*)d_in[0];
    const float* Wih = (const float*)d_in[1];
    const float* Whh = (const float*)d_in[2];
    const float* bih = (const float*)d_in[3];
    const float* bhh = (const float*)d_in[4];
    const float* W1  = (const float*)d_in[5];
    const float* b1  = (const float*)d_in[6];
    const float* W2  = (const float*)d_in[7];
    const float* b2  = (const float*)d_in[8];
    float* out = (float*)d_out;

    hipLaunchKernelGGL(lstm_fused, dim3(B_TOT / BB), dim3(1024), 0, stream,
                       x, Wih, Whh, bih, bhh, W1, b1, W2, b2, out);
}

// Round 4
// 700.581 us; speedup vs baseline: 1.1283x; 1.1283x over previous
//
#include <hip/hip_runtime.h>
#include <math.h>

// LSTMClassifier fused kernel for MI355X (gfx950) — round 3
// Round-1 structure (split-K 4-way, LDS partial combine) + asm-pinned
// weight registers to defeat loop-invariant-load rematerialization.
// B=1024, S=512, I=50, H=64, F1=32, C=2
// grid=256 (1 block/CU), 1024 threads/block, 4 batch/block.

#define B_TOT  1024
#define S_LEN  512
#define I_DIM  50
#define H_DIM  64
#define G4     256          // 4*H
#define KTOT   114          // I_DIM + H_DIM
#define KPAD   116          // padded to 4*29
#define KPL    29           // K per slice
#define BB     4            // batch per block
#define F1_DIM 32
#define C_DIM  2

__device__ __forceinline__ float fast_rcp(float x) {
    return __builtin_amdgcn_rcpf(x);
}
__device__ __forceinline__ float sigm(float v) {
    return fast_rcp(1.0f + __expf(-v));
}
__device__ __forceinline__ float tanh_fast(float v) {
    return 1.0f - 2.0f * fast_rcp(__expf(2.0f * v) + 1.0f);
}

__global__ __launch_bounds__(1024, 4)
void lstm_fused(const float* __restrict__ x,
                const float* __restrict__ W_ih, const float* __restrict__ W_hh,
                const float* __restrict__ b_ih, const float* __restrict__ b_hh,
                const float* __restrict__ W1,  const float* __restrict__ b1,
                const float* __restrict__ W2,  const float* __restrict__ b2,
                float* __restrict__ out)
{
    __shared__ __align__(16) float act[2][KPAD][BB];   // k<50: x(t); 50..113: h(t); 114/115: 0
    __shared__ float partial[4][BB][G4];               // [kslice][b][gate_row]
    __shared__ float f1buf[BB][F1_DIM];

    const int u  = threadIdx.x;              // 0..1023
    const int jg = u & 255;                  // owned gate-row
    const int kp = u >> 8;                   // K-slice 0..3
    const int k0 = kp * KPL;
    const int b0 = blockIdx.x * BB;

    // ---- 29 weight scalars (mutable so the pin-asm can claim to write) ----
#define LDW(i) float w##i = ((k0 + i) < I_DIM) \
        ? W_ih[jg * I_DIM + (k0 + i)] \
        : (((k0 + i) < KTOT) ? W_hh[jg * H_DIM + (k0 + i - I_DIM)] : 0.0f);
    LDW(0)  LDW(1)  LDW(2)  LDW(3)  LDW(4)  LDW(5)  LDW(6)  LDW(7)
    LDW(8)  LDW(9)  LDW(10) LDW(11) LDW(12) LDW(13) LDW(14) LDW(15)
    LDW(16) LDW(17) LDW(18) LDW(19) LDW(20) LDW(21) LDW(22) LDW(23)
    LDW(24) LDW(25) LDW(26) LDW(27) LDW(28)
#undef LDW

    // elementwise role (threads 0..255): cell (eb, ej)
    const int eb = u >> 6;
    const int ej = u & 63;
    float bi0 = b_ih[0 * H_DIM + ej] + b_hh[0 * H_DIM + ej];
    float bi1 = b_ih[1 * H_DIM + ej] + b_hh[1 * H_DIM + ej];
    float bi2 = b_ih[2 * H_DIM + ej] + b_hh[2 * H_DIM + ej];
    float bi3 = b_ih[3 * H_DIM + ej] + b_hh[3 * H_DIM + ej];
    float c_state = 0.0f;

    // x-prefetch role (threads 256..455): 4 batches x 50 inputs
    const int v256 = u - 256;
    const bool is_pref = (v256 >= 0) && (v256 < BB * I_DIM);
    const int pb = is_pref ? (v256 / I_DIM) : 0;
    const int pi = is_pref ? (v256 - pb * I_DIM) : 0;
    const float* xptr = x + (size_t)(b0 + pb) * (S_LEN * I_DIM) + pi;

    // ---- init: stage x(0), zero h(0), zero pad rows ----
    if (is_pref) act[0][pi][pb] = xptr[0];
    if (u < 256) act[0][I_DIM + ej][eb] = 0.0f;
    if (u < 16)  act[u >> 3][KTOT + ((u >> 2) & 1)][u & 3] = 0.0f;
    __syncthreads();

    // ---- sequential scan ----
    for (int t = 0; t < S_LEN; ++t) {
        // Pin weight/bias registers: asm may "modify" them, so the compiler
        // cannot rematerialize from global memory -> true loop-carried VGPRs.
        asm volatile("" : "+v"(w0), "+v"(w1), "+v"(w2), "+v"(w3), "+v"(w4),
                          "+v"(w5), "+v"(w6), "+v"(w7), "+v"(w8), "+v"(w9),
                          "+v"(w10), "+v"(w11), "+v"(w12), "+v"(w13), "+v"(w14),
                          "+v"(w15), "+v"(w16), "+v"(w17), "+v"(w18), "+v"(w19),
                          "+v"(w20), "+v"(w21), "+v"(w22), "+v"(w23), "+v"(w24),
                          "+v"(w25), "+v"(w26), "+v"(w27), "+v"(w28));
        asm volatile("" : "+v"(bi0), "+v"(bi1), "+v"(bi2), "+v"(bi3));

        const int cur = t & 1, nxt = cur ^ 1;

        // prefetch x(t+1) (latency hides under GEMM)
        float xpre = 0.0f;
        const bool do_pref = is_pref && (t + 1 < S_LEN);
        if (do_pref) xpre = xptr[(t + 1) * I_DIM];

        // gate GEMM over this thread's K-slice (broadcast LDS reads)
        float a0 = 0.0f, a1 = 0.0f, a2 = 0.0f, a3 = 0.0f;
#define FMA4(i) { const float4 av = *reinterpret_cast<const float4*>(&act[cur][k0 + i][0]); \
                  a0 = fmaf(w##i, av.x, a0); a1 = fmaf(w##i, av.y, a1);                     \
                  a2 = fmaf(w##i, av.z, a2); a3 = fmaf(w##i, av.w, a3); }
        FMA4(0)  FMA4(1)  FMA4(2)  FMA4(3)  FMA4(4)  FMA4(5)  FMA4(6)  FMA4(7)
        FMA4(8)  FMA4(9)  FMA4(10) FMA4(11) FMA4(12) FMA4(13) FMA4(14) FMA4(15)
        FMA4(16) FMA4(17) FMA4(18) FMA4(19) FMA4(20) FMA4(21) FMA4(22) FMA4(23)
        FMA4(24) FMA4(25) FMA4(26) FMA4(27) FMA4(28)
#undef FMA4
        partial[kp][0][jg] = a0;             // consecutive jg -> conflict-free
        partial[kp][1][jg] = a1;
        partial[kp][2][jg] = a2;
        partial[kp][3][jg] = a3;
        if (do_pref) act[nxt][pi][pb] = xpre;
        __syncthreads();

        // elementwise LSTM cell (threads 0..255)
        if (u < 256) {
            const float s0 = bi0 + partial[0][eb][0 * H_DIM + ej] + partial[1][eb][0 * H_DIM + ej]
                                 + partial[2][eb][0 * H_DIM + ej] + partial[3][eb][0 * H_DIM + ej];
            const float s1 = bi1 + partial[0][eb][1 * H_DIM + ej] + partial[1][eb][1 * H_DIM + ej]
                                 + partial[2][eb][1 * H_DIM + ej] + partial[3][eb][1 * H_DIM + ej];
            const float s2 = bi2 + partial[0][eb][2 * H_DIM + ej] + partial[1][eb][2 * H_DIM + ej]
                                 + partial[2][eb][2 * H_DIM + ej] + partial[3][eb][2 * H_DIM + ej];
            const float s3 = bi3 + partial[0][eb][3 * H_DIM + ej] + partial[1][eb][3 * H_DIM + ej]
                                 + partial[2][eb][3 * H_DIM + ej] + partial[3][eb][3 * H_DIM + ej];
            const float gi = sigm(s0);
            const float gf = sigm(s1);
            const float gg = tanh_fast(s2);
            const float go = sigm(s3);
            c_state = fmaf(gf, c_state, gi * gg);
            act[nxt][I_DIM + ej][eb] = go * tanh_fast(c_state);
        }
        __syncthreads();
    }

    // ---- classifier head; h_last in act[0][50+j][b] (S_LEN even) ----
    if (u < BB * F1_DIM) {                   // 128 threads
        const int b = u >> 5, f = u & 31;
        float acc = b1[f];
        #pragma unroll
        for (int j = 0; j < H_DIM; ++j)
            acc = fmaf(act[0][I_DIM + j][b], W1[f * H_DIM + j], acc);
        f1buf[b][f] = fmaxf(acc, 0.0f);
    }
    __syncthreads();
    if (u < BB * C_DIM) {                    // 8 threads
        const int b = u >> 1, cl = u & 1;
        float acc = b2[cl];
        #pragma unroll
        for (int f = 0; f < F1_DIM; ++f)
            acc = fmaf(f1buf[b][f], W2[cl * F1_DIM + f], acc);
        out[(size_t)(b0 + b) * C_DIM + cl] = acc;
    }
}

extern "C" void kernel_launch(void* const* d_in, const int* in_sizes, int n_in,
                              void* d_out, int out_size, void* d_ws, size_t ws_size,
                              hipStream_t stream) {
    const float* x   = (const float*)d_in[0];
    const float* Wih = (const float*)d_in[1];
    const float* Whh = (const float*)d_in[2];
    const float* bih = (const float*)d_in[3];
    const float* bhh = (const float*)d_in[4];
    const float* W1  = (const float*)d_in[5];
    const float* b1  = (const float*)d_in[6];
    const float* W2  = (const float*)d_in[7];
    const float* b2  = (const float*)d_in[8];
    float* out = (float*)d_out;

    hipLaunchKernelGGL(lstm_fused, dim3(B_TOT / BB), dim3(1024), 0, stream,
                       x, Wih, Whh, bih, bhh, W1, b1, W2, b2, out);
}

// Round 5
// 514.920 us; speedup vs baseline: 1.5352x; 1.3606x over previous
//
#include <hip/hip_runtime.h>
#include <math.h>

// LSTMClassifier fused kernel for MI355X (gfx950) — round 4: MFMA recurrence
// B=1024, S=512, I=50, H=64, F1=32, C=2
// grid=256 (1 block/CU), 256 threads (4 waves), 4 batch/block.
// Gate GEMM G[4][256] = act[114] x W^T via v_mfma_f32_16x16x32_bf16:
//   M = batch (rows 0..3 of 16 used), N = gate rows, K = 128 (padded).
//   3-term bf16 split (Ahi*Bhi + Ahi*Blo + Alo*Bhi) for ~fp32 accuracy.
// Wave w owns N-tiles {w, w+4, w+8, w+12} -> all 4 gates of units 16w..16w+15,
// so the LSTM cell update is wave-local (lanes 0..15, 4 batches each).

#define S_LEN  512
#define I_DIM  50
#define H_DIM  64
#define BB     4
#define KROW   40          // padded k-extent (bf16 elems) per k-tile row
#define F1_DIM 32
#define C_DIM  2

typedef __attribute__((ext_vector_type(8))) short short8;
typedef __attribute__((ext_vector_type(4))) float f32x4;

__device__ __forceinline__ float fast_rcp(float x) { return __builtin_amdgcn_rcpf(x); }
__device__ __forceinline__ float sigm(float v) { return fast_rcp(1.0f + __expf(-v)); }
__device__ __forceinline__ float tanh_fast(float v) {
    return 1.0f - 2.0f * fast_rcp(__expf(2.0f * v) + 1.0f);
}

__device__ __forceinline__ unsigned short bf16_rne(float f) {
    unsigned b = __float_as_uint(f);
    unsigned r = b + 0x7FFF + ((b >> 16) & 1);
    return (unsigned short)(r >> 16);
}
__device__ __forceinline__ float bf16f(unsigned short h) {
    return __uint_as_float(((unsigned)h) << 16);
}

// One weight fragment pair (hi/lo) for MFMA B operand.
// B[k][n] = W[n][k]; lane holds n = c, k = kt*32 + hk*8 + j (j=0..7).
template <int KT>
__device__ __forceinline__ void load_bfrag(const float* __restrict__ Wih,
                                           const float* __restrict__ Whh,
                                           int n_glob, int hk,
                                           short8& bh, short8& bl) {
    #pragma unroll
    for (int j = 0; j < 8; ++j) {
        const int kk = KT * 32 + hk * 8 + j;
        float wv;
        if (KT < 2) wv = (kk < I_DIM) ? Wih[n_glob * I_DIM + kk] : 0.0f;
        else        wv = Whh[n_glob * H_DIM + (kk - 64)];
        const unsigned short h = bf16_rne(wv);
        bh[j] = (short)h;
        bl[j] = (short)bf16_rne(wv - bf16f(h));
    }
}

__global__ __launch_bounds__(256, 1)
void lstm_mfma(const float* __restrict__ x,
               const float* __restrict__ W_ih, const float* __restrict__ W_hh,
               const float* __restrict__ b_ih, const float* __restrict__ b_hh,
               const float* __restrict__ W1,  const float* __restrict__ b1,
               const float* __restrict__ W2,  const float* __restrict__ b2,
               float* __restrict__ out)
{
    // A-operand staging: [ktile][m=16][k=32 (+8 pad)] bf16, hi and lo planes.
    // ktiles 0,1 = x(t) (k 0..49 + pad); ktiles 2,3 = h(t) (64 units).
    __shared__ __align__(16) unsigned short Ahi[4][16][KROW];
    __shared__ __align__(16) unsigned short Alo[4][16][KROW];
    __shared__ float f1buf[BB][F1_DIM];

    const int u  = threadIdx.x;      // 0..255
    const int w  = u >> 6;           // wave 0..3
    const int l  = u & 63;           // lane
    const int c  = l & 15;           // tile row/col index (m for A, n for B/D)
    const int hk = l >> 4;           // k-half 0..3
    const int b0 = blockIdx.x * BB;

    // ---- weight fragments (resident for the whole scan) ----
    // wave w, q-th tile -> gate q, units 16w..16w+15 (n_glob = 64q + 16w + c)
#define LB(q, kt) short8 bh##q##kt, bl##q##kt; \
    load_bfrag<kt>(W_ih, W_hh, 64 * (q) + 16 * w + c, hk, bh##q##kt, bl##q##kt);
    LB(0,0) LB(0,1) LB(0,2) LB(0,3)
    LB(1,0) LB(1,1) LB(1,2) LB(1,3)
    LB(2,0) LB(2,1) LB(2,2) LB(2,3)
    LB(3,0) LB(3,1) LB(3,2) LB(3,3)
#undef LB

    // ---- per-lane cell role: unit ej = 16w + c (valid in lanes hk==0) ----
    const int ej = 16 * w + c;
    float bia0 = b_ih[0 * H_DIM + ej] + b_hh[0 * H_DIM + ej];
    float bia1 = b_ih[1 * H_DIM + ej] + b_hh[1 * H_DIM + ej];
    float bia2 = b_ih[2 * H_DIM + ej] + b_hh[2 * H_DIM + ej];
    float bia3 = b_ih[3 * H_DIM + ej] + b_hh[3 * H_DIM + ej];
    float cst0 = 0.0f, cst1 = 0.0f, cst2 = 0.0f, cst3 = 0.0f;

    // ---- x staging role: threads 0..199 -> (batch pb, input pi) ----
    const bool isp = (u < BB * I_DIM);
    int pb = u / I_DIM; if (pb > 3) pb = 3;
    const int pi = u - pb * I_DIM;
    const float* xp = x + ((size_t)(b0 + pb) * S_LEN) * I_DIM + pi;

    // ---- init: zero both A planes (covers m=4..15 rows & k-pads forever) ----
    {
        unsigned* za = (unsigned*)Ahi;
        unsigned* zb = (unsigned*)Alo;
        #pragma unroll
        for (int i = 0; i < 5; ++i) { za[u + 256 * i] = 0u; zb[u + 256 * i] = 0u; }
    }
    __syncthreads();
    if (isp) {   // stage x(t=0)
        const float v = xp[0];
        const unsigned short h = bf16_rne(v);
        Ahi[pi >> 5][pb][pi & 31] = h;
        Alo[pi >> 5][pb][pi & 31] = bf16_rne(v - bf16f(h));
    }
    __syncthreads();

    // ---- sequential scan over time ----
    for (int t = 0; t < S_LEN; ++t) {
        // keep weight frags / biases loop-resident
        asm volatile("" : "+v"(bh00), "+v"(bh01), "+v"(bh02), "+v"(bh03));
        asm volatile("" : "+v"(bh10), "+v"(bh11), "+v"(bh12), "+v"(bh13));
        asm volatile("" : "+v"(bh20), "+v"(bh21), "+v"(bh22), "+v"(bh23));
        asm volatile("" : "+v"(bh30), "+v"(bh31), "+v"(bh32), "+v"(bh33));
        asm volatile("" : "+v"(bl00), "+v"(bl01), "+v"(bl02), "+v"(bl03));
        asm volatile("" : "+v"(bl10), "+v"(bl11), "+v"(bl12), "+v"(bl13));
        asm volatile("" : "+v"(bl20), "+v"(bl21), "+v"(bl22), "+v"(bl23));
        asm volatile("" : "+v"(bl30), "+v"(bl31), "+v"(bl32), "+v"(bl33));
        asm volatile("" : "+v"(bia0), "+v"(bia1), "+v"(bia2), "+v"(bia3));

        // prefetch x(t+1) (HBM latency hides under MFMA phase)
        float xnext = 0.0f;
        const bool dox = isp && (t + 1 < S_LEN);
        if (dox) xnext = xp[(size_t)(t + 1) * I_DIM];

        // A fragments: lane reads A[m=c][k = hk*8 .. hk*8+7] of each k-tile
#define LDA(kt) \
        const short8 ah##kt = *reinterpret_cast<const short8*>(&Ahi[kt][c][hk * 8]); \
        const short8 al##kt = *reinterpret_cast<const short8*>(&Alo[kt][c][hk * 8]);
        LDA(0) LDA(1) LDA(2) LDA(3)
#undef LDA

        f32x4 acc0 = {bia0, bia0, bia0, bia0};
        f32x4 acc1 = {bia1, bia1, bia1, bia1};
        f32x4 acc2 = {bia2, bia2, bia2, bia2};
        f32x4 acc3 = {bia3, bia3, bia3, bia3};

        // all waves' LDS reads done -> epilogue writes (below) are safe
        __syncthreads();

#define MM(q, kt) \
        acc##q = __builtin_amdgcn_mfma_f32_16x16x32_bf16(ah##kt, bh##q##kt, acc##q, 0, 0, 0); \
        acc##q = __builtin_amdgcn_mfma_f32_16x16x32_bf16(ah##kt, bl##q##kt, acc##q, 0, 0, 0); \
        acc##q = __builtin_amdgcn_mfma_f32_16x16x32_bf16(al##kt, bh##q##kt, acc##q, 0, 0, 0);
        MM(0,0) MM(1,0) MM(2,0) MM(3,0)
        MM(0,1) MM(1,1) MM(2,1) MM(3,1)
        MM(0,2) MM(1,2) MM(2,2) MM(3,2)
        MM(0,3) MM(1,3) MM(2,3) MM(3,3)
#undef MM

        // ---- cell update: lanes hk==0 own (unit ej) x 4 batches ----
        if (hk == 0) {
            const int kt2 = 2 + (ej >> 5), kc2 = ej & 31;
#define CELL(b) { \
            const float gi = sigm(acc0[b]); \
            const float gf = sigm(acc1[b]); \
            const float gg = tanh_fast(acc2[b]); \
            const float go = sigm(acc3[b]); \
            cst##b = fmaf(gf, cst##b, gi * gg); \
            const float hv = go * tanh_fast(cst##b); \
            const unsigned short hh = bf16_rne(hv); \
            Ahi[kt2][b][kc2] = hh; \
            Alo[kt2][b][kc2] = bf16_rne(hv - bf16f(hh)); }
            CELL(0) CELL(1) CELL(2) CELL(3)
#undef CELL
        }
        // stage x(t+1)
        if (dox) {
            const unsigned short h = bf16_rne(xnext);
            Ahi[pi >> 5][pb][pi & 31] = h;
            Alo[pi >> 5][pb][pi & 31] = bf16_rne(xnext - bf16f(h));
        }
        __syncthreads();
    }

    // ---- classifier head; h_last (hi+lo ~ fp32) in ktiles 2,3 ----
    if (u < BB * F1_DIM) {                   // 128 threads
        const int b = u >> 5, f = u & 31;
        float acc = b1[f];
        #pragma unroll
        for (int j = 0; j < H_DIM; ++j) {
            const float hj = bf16f(Ahi[2 + (j >> 5)][b][j & 31])
                           + bf16f(Alo[2 + (j >> 5)][b][j & 31]);
            acc = fmaf(hj, W1[f * H_DIM + j], acc);
        }
        f1buf[b][f] = fmaxf(acc, 0.0f);
    }
    __syncthreads();
    if (u < BB * C_DIM) {                    // 8 threads
        const int b = u >> 1, cl = u & 1;
        float acc = b2[cl];
        #pragma unroll
        for (int f = 0; f < F1_DIM; ++f)
            acc = fmaf(f1buf[b][f], W2[cl * F1_DIM + f], acc);
        out[(size_t)(b0 + b) * C_DIM + cl] = acc;
    }
}

extern "C" void kernel_launch(void* const* d_in, const int* in_sizes, int n_in,
                              void* d_out, int out_size, void* d_ws, size_t ws_size,
                              hipStream_t stream) {
    const float* x   = (const float*)d_in[0];
    const float* Wih = (const float*)d_in[1];
    const float* Whh = (const float*)d_in[2];
    const float* bih = (const float*)d_in[3];
    const float* bhh = (const float*)d_in[4];
    const float* W1  = (const float*)d_in[5];
    const float* b1  = (const float*)d_in[6];
    const float* W2  = (const float*)d_in[7];
    const float* b2  = (const float*)d_in[8];
    float* out = (float*)d_out;

    hipLaunchKernelGGL(lstm_mfma, dim3(256), dim3(256), 0, stream,
                       x, Wih, Whh, bih, bhh, W1, b1, W2, b2, out);
}

// Round 6
// 507.688 us; speedup vs baseline: 1.5571x; 1.0142x over previous
//
#include <hip/hip_runtime.h>
#include <math.h>

// LSTMClassifier fused kernel for MI355X (gfx950) — round 5
// MFMA recurrence + double-buffered LDS A-tile -> ONE barrier per step,
// x(t+1) global load gets the whole step to land before the barrier drain,
// and split accumulators (x-ktiles vs h-ktiles) halve MFMA chain depth.
// B=1024, S=512, I=50, H=64, F1=32, C=2
// grid=256 (1 block/CU), 256 threads (4 waves), 4 batch/block.
// Gate GEMM via v_mfma_f32_16x16x32_bf16, 3-term bf16 split (~fp32 accuracy).
// Wave w owns all 4 gates of units 16w..16w+15 -> cell update is wave-local.

#define S_LEN  512
#define I_DIM  50
#define H_DIM  64
#define BB     4
#define KROW   40          // padded k-extent (shorts) per tile row: 80B stride
#define F1_DIM 32
#define C_DIM  2

typedef __attribute__((ext_vector_type(8))) short short8;
typedef __attribute__((ext_vector_type(4))) float f32x4;

__device__ __forceinline__ float fast_rcp(float x) { return __builtin_amdgcn_rcpf(x); }
__device__ __forceinline__ float sigm(float v) { return fast_rcp(1.0f + __expf(-v)); }
__device__ __forceinline__ float tanh_fast(float v) {
    return 1.0f - 2.0f * fast_rcp(__expf(2.0f * v) + 1.0f);
}

__device__ __forceinline__ unsigned short bf16_rne(float f) {
    unsigned b = __float_as_uint(f);
    unsigned r = b + 0x7FFF + ((b >> 16) & 1);
    return (unsigned short)(r >> 16);
}
__device__ __forceinline__ float bf16f(unsigned short h) {
    return __uint_as_float(((unsigned)h) << 16);
}

// Weight fragment pair (hi/lo) for MFMA B operand.
// B[k][n] = W[n][k]; lane holds n = c, k = kt*32 + hk*8 + j (j=0..7).
template <int KT>
__device__ __forceinline__ void load_bfrag(const float* __restrict__ Wih,
                                           const float* __restrict__ Whh,
                                           int n_glob, int hk,
                                           short8& bh, short8& bl) {
    #pragma unroll
    for (int j = 0; j < 8; ++j) {
        const int kk = KT * 32 + hk * 8 + j;
        float wv;
        if (KT < 2) wv = (kk < I_DIM) ? Wih[n_glob * I_DIM + kk] : 0.0f;
        else        wv = Whh[n_glob * H_DIM + (kk - 64)];
        const unsigned short h = bf16_rne(wv);
        bh[j] = (short)h;
        bl[j] = (short)bf16_rne(wv - bf16f(h));
    }
}

__global__ __launch_bounds__(256, 1)
void lstm_mfma(const float* __restrict__ x,
               const float* __restrict__ W_ih, const float* __restrict__ W_hh,
               const float* __restrict__ b_ih, const float* __restrict__ b_hh,
               const float* __restrict__ W1,  const float* __restrict__ b1,
               const float* __restrict__ W2,  const float* __restrict__ b2,
               float* __restrict__ out)
{
    // Double-buffered A-operand: [buf][ktile][m=16][KROW] bf16 hi/lo planes.
    // ktiles 0,1 = x(t); ktiles 2,3 = h(t).
    __shared__ __align__(16) unsigned short Ahi[2][4][16][KROW];
    __shared__ __align__(16) unsigned short Alo[2][4][16][KROW];
    __shared__ float f1buf[BB][F1_DIM];

    const int u  = threadIdx.x;      // 0..255
    const int w  = u >> 6;           // wave 0..3
    const int l  = u & 63;           // lane
    const int c  = l & 15;           // m for A-read, n for B/D
    const int hk = l >> 4;           // k-quarter 0..3
    const int b0 = blockIdx.x * BB;

    // ---- weight fragments (resident for the whole scan) ----
#define LB(q, kt) short8 bh##q##kt, bl##q##kt; \
    load_bfrag<kt>(W_ih, W_hh, 64 * (q) + 16 * w + c, hk, bh##q##kt, bl##q##kt);
    LB(0,0) LB(0,1) LB(0,2) LB(0,3)
    LB(1,0) LB(1,1) LB(1,2) LB(1,3)
    LB(2,0) LB(2,1) LB(2,2) LB(2,3)
    LB(3,0) LB(3,1) LB(3,2) LB(3,3)
#undef LB

    // ---- per-lane cell role: unit ej = 16w + c (active in lanes hk==0) ----
    const int ej = 16 * w + c;
    float bia0 = b_ih[0 * H_DIM + ej] + b_hh[0 * H_DIM + ej];
    float bia1 = b_ih[1 * H_DIM + ej] + b_hh[1 * H_DIM + ej];
    float bia2 = b_ih[2 * H_DIM + ej] + b_hh[2 * H_DIM + ej];
    float bia3 = b_ih[3 * H_DIM + ej] + b_hh[3 * H_DIM + ej];
    float cst0 = 0.0f, cst1 = 0.0f, cst2 = 0.0f, cst3 = 0.0f;

    // ---- x staging role: threads 0..199 -> (batch pb, input pi) ----
    const bool isp = (u < BB * I_DIM);
    int pb = u / I_DIM; if (pb > 3) pb = 3;
    const int pi = u - pb * I_DIM;
    const float* xp = x + ((size_t)(b0 + pb) * S_LEN) * I_DIM + pi;
    const int skt = pi >> 5, skc = pi & 31;      // staging target in ktile 0/1

    // ---- init: zero both buffers of both planes (m=4..15 rows stay 0) ----
    {
        unsigned* za = (unsigned*)Ahi;           // 2*4*16*20 = 2560 u32
        unsigned* zb = (unsigned*)Alo;
        #pragma unroll
        for (int i = 0; i < 10; ++i) { za[u + 256 * i] = 0u; zb[u + 256 * i] = 0u; }
    }
    __syncthreads();
    if (isp) {   // stage x(t=0) into buf 0
        const float v = xp[0];
        const unsigned short h = bf16_rne(v);
        Ahi[0][skt][pb][skc] = h;
        Alo[0][skt][pb][skc] = bf16_rne(v - bf16f(h));
    }
    __syncthreads();

    // ---- sequential scan: ONE barrier per step (double-buffered tile) ----
    for (int t = 0; t < S_LEN; ++t) {
        // keep weight frags / biases loop-resident
        asm volatile("" : "+v"(bh00), "+v"(bh01), "+v"(bh02), "+v"(bh03));
        asm volatile("" : "+v"(bh10), "+v"(bh11), "+v"(bh12), "+v"(bh13));
        asm volatile("" : "+v"(bh20), "+v"(bh21), "+v"(bh22), "+v"(bh23));
        asm volatile("" : "+v"(bh30), "+v"(bh31), "+v"(bh32), "+v"(bh33));
        asm volatile("" : "+v"(bl00), "+v"(bl01), "+v"(bl02), "+v"(bl03));
        asm volatile("" : "+v"(bl10), "+v"(bl11), "+v"(bl12), "+v"(bl13));
        asm volatile("" : "+v"(bl20), "+v"(bl21), "+v"(bl22), "+v"(bl23));
        asm volatile("" : "+v"(bl30), "+v"(bl31), "+v"(bl32), "+v"(bl33));
        asm volatile("" : "+v"(bia0), "+v"(bia1), "+v"(bia2), "+v"(bia3));

        const int cur = t & 1, nxt = cur ^ 1;

        // issue x(t+1) load NOW; it has the whole step before the barrier drain
        float xnext = 0.0f;
        const bool dox = isp && (t + 1 < S_LEN);
        if (dox) xnext = xp[(size_t)(t + 1) * I_DIM];

        // A fragments from buf[cur]
#define LDA(kt) \
        const short8 ah##kt = *reinterpret_cast<const short8*>(&Ahi[cur][kt][c][hk * 8]); \
        const short8 al##kt = *reinterpret_cast<const short8*>(&Alo[cur][kt][c][hk * 8]);
        LDA(0) LDA(1) LDA(2) LDA(3)
#undef LDA

        f32x4 accA0 = {bia0, bia0, bia0, bia0};  // x-ktiles (+bias)
        f32x4 accA1 = {bia1, bia1, bia1, bia1};
        f32x4 accA2 = {bia2, bia2, bia2, bia2};
        f32x4 accA3 = {bia3, bia3, bia3, bia3};
        f32x4 accB0 = {0.f, 0.f, 0.f, 0.f};      // h-ktiles
        f32x4 accB1 = {0.f, 0.f, 0.f, 0.f};
        f32x4 accB2 = {0.f, 0.f, 0.f, 0.f};
        f32x4 accB3 = {0.f, 0.f, 0.f, 0.f};

#define MM(dst, q, kt) \
        dst = __builtin_amdgcn_mfma_f32_16x16x32_bf16(ah##kt, bh##q##kt, dst, 0, 0, 0); \
        dst = __builtin_amdgcn_mfma_f32_16x16x32_bf16(ah##kt, bl##q##kt, dst, 0, 0, 0); \
        dst = __builtin_amdgcn_mfma_f32_16x16x32_bf16(al##kt, bh##q##kt, dst, 0, 0, 0);
        MM(accA0, 0, 0) MM(accA1, 1, 0) MM(accA2, 2, 0) MM(accA3, 3, 0)
        MM(accA0, 0, 1) MM(accA1, 1, 1) MM(accA2, 2, 1) MM(accA3, 3, 1)
        MM(accB0, 0, 2) MM(accB1, 1, 2) MM(accB2, 2, 2) MM(accB3, 3, 2)
        MM(accB0, 0, 3) MM(accB1, 1, 3) MM(accB2, 2, 3) MM(accB3, 3, 3)
#undef MM

        // ---- cell update: lanes hk==0 own unit ej x 4 batches ----
        if (hk == 0) {
            const int kt2 = 2 + (ej >> 5), kc2 = ej & 31;
#define CELL(b) { \
            const float gi = sigm(accA0[b] + accB0[b]); \
            const float gf = sigm(accA1[b] + accB1[b]); \
            const float gg = tanh_fast(accA2[b] + accB2[b]); \
            const float go = sigm(accA3[b] + accB3[b]); \
            cst##b = fmaf(gf, cst##b, gi * gg); \
            const float hv = go * tanh_fast(cst##b); \
            const unsigned short hh = bf16_rne(hv); \
            Ahi[nxt][kt2][b][kc2] = hh; \
            Alo[nxt][kt2][b][kc2] = bf16_rne(hv - bf16f(hh)); }
            CELL(0) CELL(1) CELL(2) CELL(3)
#undef CELL
        }
        // stage x(t+1) into buf[nxt] (load issued ~a full step ago)
        if (dox) {
            const unsigned short h = bf16_rne(xnext);
            Ahi[nxt][skt][pb][skc] = h;
            Alo[nxt][skt][pb][skc] = bf16_rne(xnext - bf16f(h));
        }
        __syncthreads();
    }

    // ---- classifier head; h_last (hi+lo ~ fp32) in buf 0, ktiles 2,3 ----
    if (u < BB * F1_DIM) {                   // 128 threads
        const int b = u >> 5, f = u & 31;
        float acc = b1[f];
        #pragma unroll
        for (int j = 0; j < H_DIM; ++j) {
            const float hj = bf16f(Ahi[0][2 + (j >> 5)][b][j & 31])
                           + bf16f(Alo[0][2 + (j >> 5)][b][j & 31]);
            acc = fmaf(hj, W1[f * H_DIM + j], acc);
        }
        f1buf[b][f] = fmaxf(acc, 0.0f);
    }
    __syncthreads();
    if (u < BB * C_DIM) {                    // 8 threads
        const int b = u >> 1, cl = u & 1;
        float acc = b2[cl];
        #pragma unroll
        for (int f = 0; f < F1_DIM; ++f)
            acc = fmaf(f1buf[b][f], W2[cl * F1_DIM + f], acc);
        out[(size_t)(b0 + b) * C_DIM + cl] = acc;
    }
}

extern "C" void kernel_launch(void* const* d_in, const int* in_sizes, int n_in,
                              void* d_out, int out_size, void* d_ws, size_t ws_size,
                              hipStream_t stream) {
    const float* x   = (const float*)d_in[0];
    const float* Wih = (const float*)d_in[1];
    const float* Whh = (const float*)d_in[2];
    const float* bih = (const float*)d_in[3];
    const float* bhh = (const float*)d_in[4];
    const float* W1  = (const float*)d_in[5];
    const float* b1  = (const float*)d_in[6];
    const float* W2  = (const float*)d_in[7];
    const float* b2  = (const float*)d_in[8];
    float* out = (float*)d_out;

    hipLaunchKernelGGL(lstm_mfma, dim3(256), dim3(256), 0, stream,
                       x, Wih, Whh, bih, bhh, W1, b1, W2, b2, out);
}

// Round 7
// 387.885 us; speedup vs baseline: 2.0380x; 1.3089x over previous
//
#include <hip/hip_runtime.h>
#include <math.h>

// LSTMClassifier fused kernel for MI355X (gfx950) — round 6
// 8-wave role split: waves 0-3 = h·W_hh MFMA + cell update;
// waves 4-7 = x·W_ih MFMA (bias folded) + x staging. 2 waves/SIMD
// interleave to hide LDS/MFMA latency. Batches staggered to A-rows
// {0,4,8,12} so the cell update uses all 64 lanes (batch = lane>>4).
// B=1024, S=512, I=50, H=64, F1=32, C=2
// grid=256 (1 block/CU), 512 threads, 4 batch/block.
// v_mfma_f32_16x16x32_bf16, 3-term bf16 split (~fp32 accuracy).

#define S_LEN  512
#define I_DIM  50
#define H_DIM  64
#define BB     4
#define KROW   40          // A-row stride in shorts (80B)
#define F1_DIM 32
#define C_DIM  2
#define PPAD   72          // pbuf unit-dim pad (72 words: 2-way conflicts only)

typedef __attribute__((ext_vector_type(8))) short short8;
typedef __attribute__((ext_vector_type(4))) float f32x4;

__device__ __forceinline__ float fast_rcp(float x) { return __builtin_amdgcn_rcpf(x); }
__device__ __forceinline__ float sigm(float v) { return fast_rcp(1.0f + __expf(-v)); }
__device__ __forceinline__ float tanh_fast(float v) {
    return 1.0f - 2.0f * fast_rcp(__expf(2.0f * v) + 1.0f);
}

__device__ __forceinline__ unsigned short bf16_rne(float f) {
    unsigned b = __float_as_uint(f);
    unsigned r = b + 0x7FFF + ((b >> 16) & 1);
    return (unsigned short)(r >> 16);
}
__device__ __forceinline__ float bf16f(unsigned short h) {
    return __uint_as_float(((unsigned)h) << 16);
}

// Weight fragment pair (hi/lo) for MFMA B operand.
// B[k][n] = W[n][k]; lane holds n = n_glob, k = ktg*32 + hk*8 + j.
__device__ __forceinline__ void load_bfrag(const float* __restrict__ Wih,
                                           const float* __restrict__ Whh,
                                           int ktg, int n_glob, int hk,
                                           short8& bh, short8& bl) {
    #pragma unroll
    for (int j = 0; j < 8; ++j) {
        const int kk = ktg * 32 + hk * 8 + j;
        float wv;
        if (ktg < 2) wv = (kk < I_DIM) ? Wih[n_glob * I_DIM + kk] : 0.0f;
        else         wv = Whh[n_glob * H_DIM + (kk - 64)];
        const unsigned short h = bf16_rne(wv);
        bh[j] = (short)h;
        bl[j] = (short)bf16_rne(wv - bf16f(h));
    }
}

__global__ __launch_bounds__(512, 2)
void lstm_mfma(const float* __restrict__ x,
               const float* __restrict__ W_ih, const float* __restrict__ W_hh,
               const float* __restrict__ b_ih, const float* __restrict__ b_hh,
               const float* __restrict__ W1,  const float* __restrict__ b1,
               const float* __restrict__ W2,  const float* __restrict__ b2,
               float* __restrict__ out)
{
    // Double-buffered A-operand: [buf][ktile][m=16][KROW] bf16 hi/lo planes.
    // ktiles 0,1 = x(t); ktiles 2,3 = h(t). Batch b lives in row 4b.
    __shared__ __align__(16) unsigned short Ahi[2][4][16][KROW];
    __shared__ __align__(16) unsigned short Alo[2][4][16][KROW];
    __shared__ float pbuf[4][4][PPAD];   // [gate][batch][unit]: x-part + bias
    __shared__ float f1buf[BB][F1_DIM];

    const int u    = threadIdx.x;        // 0..511
    const int w    = u >> 6;             // wave 0..7
    const int is_h = (w < 4);            // role
    const int wq   = w & 3;              // role-local wave id
    const int l    = u & 63;
    const int c    = l & 15;             // col (n for B/D, row for A-read)
    const int hk   = l >> 4;             // k-quarter / batch in cell phase
    const int ej   = 16 * wq + c;        // owned hidden unit (gate col)
    const int b0   = blockIdx.x * BB;
    const int ktb  = is_h ? 2 : 0;       // role's ktile base

    // ---- weight fragments: gate q, role ktiles ktb+0, ktb+1 ----
#define LB(q, kt) short8 bh##q##kt, bl##q##kt; \
    load_bfrag(W_ih, W_hh, ktb + kt, 64 * (q) + ej, hk, bh##q##kt, bl##q##kt);
    LB(0,0) LB(0,1) LB(1,0) LB(1,1)
    LB(2,0) LB(2,1) LB(3,0) LB(3,1)
#undef LB

    // bias (x-waves fold it into their accumulators)
    const float ini0 = is_h ? 0.0f : (b_ih[0 * H_DIM + ej] + b_hh[0 * H_DIM + ej]);
    const float ini1 = is_h ? 0.0f : (b_ih[1 * H_DIM + ej] + b_hh[1 * H_DIM + ej]);
    const float ini2 = is_h ? 0.0f : (b_ih[2 * H_DIM + ej] + b_hh[2 * H_DIM + ej]);
    const float ini3 = is_h ? 0.0f : (b_ih[3 * H_DIM + ej] + b_hh[3 * H_DIM + ej]);
    float cst = 0.0f;                    // cell state (h-waves; batch hk, unit ej)

    // ---- x staging role: x-wave threads v<200 -> (batch pb, input pi) ----
    const int  v   = u - 256;            // x-waves: 0..255
    const bool isp = (!is_h) && (v >= 0) && (v < BB * I_DIM);
    const int  pb  = isp ? (v / I_DIM) : 0;
    const int  pi  = isp ? (v - pb * I_DIM) : 0;
    const float* xp = x + ((size_t)(b0 + pb) * S_LEN) * I_DIM + pi;
    const int skt = pi >> 5, skc = pi & 31, srw = 4 * pb;

    // ---- init: zero both buffers of both planes ----
    {
        unsigned* za = (unsigned*)Ahi;   // 2*4*16*40/2 = 2560 u32 each plane
        unsigned* zb = (unsigned*)Alo;
        #pragma unroll
        for (int i = 0; i < 5; ++i) { za[u + 512 * i] = 0u; zb[u + 512 * i] = 0u; }
    }
    __syncthreads();
    if (isp) {   // stage x(t=0) into buf 0 (h rows stay 0 = h0)
        const float vv = xp[0];
        const unsigned short h = bf16_rne(vv);
        Ahi[0][skt][srw][skc] = h;
        Alo[0][skt][srw][skc] = bf16_rne(vv - bf16f(h));
    }
    __syncthreads();

    // ---- sequential scan: phases A (MFMA) / B (cell + staging) ----
    for (int t = 0; t < S_LEN; ++t) {
        asm volatile("" : "+v"(bh00), "+v"(bh01), "+v"(bh10), "+v"(bh11),
                          "+v"(bh20), "+v"(bh21), "+v"(bh30), "+v"(bh31));
        asm volatile("" : "+v"(bl00), "+v"(bl01), "+v"(bl10), "+v"(bl11),
                          "+v"(bl20), "+v"(bl21), "+v"(bl30), "+v"(bl31));

        const int cur = t & 1, nxt = cur ^ 1;

        // x-waves: issue x(t+1) load first (lands during phases A+B)
        float xnext = 0.0f;
        const bool dox = isp && (t + 1 < S_LEN);
        if (dox) xnext = xp[(size_t)(t + 1) * I_DIM];

        // A fragments for this role's two ktiles
        const short8 ah0 = *reinterpret_cast<const short8*>(&Ahi[cur][ktb][c][hk * 8]);
        const short8 al0 = *reinterpret_cast<const short8*>(&Alo[cur][ktb][c][hk * 8]);
        const short8 ah1 = *reinterpret_cast<const short8*>(&Ahi[cur][ktb + 1][c][hk * 8]);
        const short8 al1 = *reinterpret_cast<const short8*>(&Alo[cur][ktb + 1][c][hk * 8]);

        f32x4 acc0 = {ini0, ini0, ini0, ini0};
        f32x4 acc1 = {ini1, ini1, ini1, ini1};
        f32x4 acc2 = {ini2, ini2, ini2, ini2};
        f32x4 acc3 = {ini3, ini3, ini3, ini3};

#define MM(q) \
        acc##q = __builtin_amdgcn_mfma_f32_16x16x32_bf16(ah0, bh##q##0, acc##q, 0, 0, 0); \
        acc##q = __builtin_amdgcn_mfma_f32_16x16x32_bf16(ah0, bl##q##0, acc##q, 0, 0, 0); \
        acc##q = __builtin_amdgcn_mfma_f32_16x16x32_bf16(al0, bh##q##0, acc##q, 0, 0, 0); \
        acc##q = __builtin_amdgcn_mfma_f32_16x16x32_bf16(ah1, bh##q##1, acc##q, 0, 0, 0); \
        acc##q = __builtin_amdgcn_mfma_f32_16x16x32_bf16(ah1, bl##q##1, acc##q, 0, 0, 0); \
        acc##q = __builtin_amdgcn_mfma_f32_16x16x32_bf16(al1, bh##q##1, acc##q, 0, 0, 0);
        MM(0) MM(1) MM(2) MM(3)
#undef MM

        // x-waves publish x-part partials (batch hk in acc reg 0)
        if (!is_h) {
            pbuf[0][hk][ej] = acc0[0];
            pbuf[1][hk][ej] = acc1[0];
            pbuf[2][hk][ej] = acc2[0];
            pbuf[3][hk][ej] = acc3[0];
        }
        __syncthreads();                 // B1: partials visible

        if (is_h) {
            // cell update: all 64 lanes, batch hk, unit ej
            const float g0 = acc0[0] + pbuf[0][hk][ej];
            const float g1 = acc1[0] + pbuf[1][hk][ej];
            const float g2 = acc2[0] + pbuf[2][hk][ej];
            const float g3 = acc3[0] + pbuf[3][hk][ej];
            const float gi = sigm(g0);
            const float gf = sigm(g1);
            const float gg = tanh_fast(g2);
            const float go = sigm(g3);
            cst = fmaf(gf, cst, gi * gg);
            const float hv = go * tanh_fast(cst);
            const int kth = 2 + (ej >> 5), kc = ej & 31;
            const unsigned short hh = bf16_rne(hv);
            Ahi[nxt][kth][4 * hk][kc] = hh;
            Alo[nxt][kth][4 * hk][kc] = bf16_rne(hv - bf16f(hh));
        } else if (dox) {
            // stage x(t+1) into buf[nxt]
            const unsigned short h = bf16_rne(xnext);
            Ahi[nxt][skt][srw][skc] = h;
            Alo[nxt][skt][srw][skc] = bf16_rne(xnext - bf16f(h));
        }
        __syncthreads();                 // B2: h(t+1), x(t+1) staged
    }

    // ---- classifier head; h_last (hi+lo) in buf 0, ktiles 2,3, rows 4b ----
    if (u < BB * F1_DIM) {               // 128 threads
        const int b = u >> 5, f = u & 31;
        float acc = b1[f];
        #pragma unroll
        for (int j = 0; j < H_DIM; ++j) {
            const float hj = bf16f(Ahi[0][2 + (j >> 5)][4 * b][j & 31])
                           + bf16f(Alo[0][2 + (j >> 5)][4 * b][j & 31]);
            acc = fmaf(hj, W1[f * H_DIM + j], acc);
        }
        f1buf[b][f] = fmaxf(acc, 0.0f);
    }
    __syncthreads();
    if (u < BB * C_DIM) {                // 8 threads
        const int b = u >> 1, cl = u & 1;
        float acc = b2[cl];
        #pragma unroll
        for (int f = 0; f < F1_DIM; ++f)
            acc = fmaf(f1buf[b][f], W2[cl * F1_DIM + f], acc);
        out[(size_t)(b0 + b) * C_DIM + cl] = acc;
    }
}

extern "C" void kernel_launch(void* const* d_in, const int* in_sizes, int n_in,
                              void* d_out, int out_size, void* d_ws, size_t ws_size,
                              hipStream_t stream) {
    const float* x   = (const float*)d_in[0];
    const float* Wih = (const float*)d_in[1];
    const float* Whh = (const float*)d_in[2];
    const float* bih = (const float*)d_in[3];
    const float* bhh = (const float*)d_in[4];
    const float* W1  = (const float*)d_in[5];
    const float* b1  = (const float*)d_in[6];
    const float* W2  = (const float*)d_in[7];
    const float* b2  = (const float*)d_in[8];
    float* out = (float*)d_out;

    hipLaunchKernelGGL(lstm_mfma, dim3(256), dim3(512), 0, stream,
                       x, Wih, Whh, bih, bhh, W1, b1, W2, b2, out);
}

// Round 9
// 330.132 us; speedup vs baseline: 2.3945x; 1.1749x over previous
//
#include <hip/hip_runtime.h>
#include <math.h>

// LSTMClassifier fused kernel for MI355X (gfx950) — round 8 (r7 + compile fix)
// Gate-permuted N layout: wave w's two N-tiles hold ALL 4 gates of units
// 8w..8w+7 (tile A: i|f, tile B: g|o) -> gates complete in-wave, no partial
// exchange, ONE barrier/step. Cross-step pipeline: x·W_ih MFMAs for step t+1
// issue during step t's cell chain (separate MFMA/VALU pipes).
// B=1024, S=512, I=50, H=64, F1=32, C=2
// grid=256 (1 block/CU), 512 threads (8 waves), 4 batch/block (A-rows 0,4,8,12).
// v_mfma_f32_16x16x32_bf16, 3-term bf16 split (~fp32 accuracy).

#define S_LEN  512
#define I_DIM  50
#define H_DIM  64
#define BB     4
#define KROW   40          // A-row stride in shorts (80B)
#define F1_DIM 32
#define C_DIM  2

typedef __attribute__((ext_vector_type(8))) short short8;
typedef __attribute__((ext_vector_type(4))) float f32x4;

__device__ __forceinline__ float fast_rcp(float x) { return __builtin_amdgcn_rcpf(x); }
__device__ __forceinline__ float sigm(float v) { return fast_rcp(1.0f + __expf(-v)); }
__device__ __forceinline__ float tanh_fast(float v) {
    return 1.0f - 2.0f * fast_rcp(__expf(2.0f * v) + 1.0f);
}
__device__ __forceinline__ unsigned short bf16_rne(float f) {
    unsigned b = __float_as_uint(f);
    unsigned r = b + 0x7FFF + ((b >> 16) & 1);
    return (unsigned short)(r >> 16);
}
__device__ __forceinline__ float bf16f(unsigned short h) {
    return __uint_as_float(((unsigned)h) << 16);
}

// Weight fragment pair (hi/lo). B[k][n]=W[row][k]; lane holds k = ktg*32+hk*8+j.
// ktg 0,1 -> W_ih (k<50, else 0); ktg 2,3 -> W_hh (k-64).
__device__ __forceinline__ void load_wfrag(const float* __restrict__ Wih,
                                           const float* __restrict__ Whh,
                                           int ktg, int row, int hk,
                                           short8& bh, short8& bl) {
    #pragma unroll
    for (int j = 0; j < 8; ++j) {
        const int kk = ktg * 32 + hk * 8 + j;
        float wv;
        if (ktg < 2) wv = (kk < I_DIM) ? Wih[row * I_DIM + kk] : 0.0f;
        else         wv = Whh[row * H_DIM + (kk - 64)];
        const unsigned short h = bf16_rne(wv);
        bh[j] = (short)h;
        bl[j] = (short)bf16_rne(wv - bf16f(h));
    }
}

__global__ __launch_bounds__(512, 2)
void lstm_mfma(const float* __restrict__ x,
               const float* __restrict__ W_ih, const float* __restrict__ W_hh,
               const float* __restrict__ b_ih, const float* __restrict__ b_hh,
               const float* __restrict__ W1,  const float* __restrict__ b1,
               const float* __restrict__ W2,  const float* __restrict__ b2,
               float* __restrict__ out)
{
    // A-operand stages, double-buffered: [buf][ktile][m=16][KROW], hi/lo planes.
    __shared__ __align__(16) unsigned short Hhi[2][2][16][KROW];
    __shared__ __align__(16) unsigned short Hlo[2][2][16][KROW];
    __shared__ __align__(16) unsigned short Xhi[2][2][16][KROW];
    __shared__ __align__(16) unsigned short Xlo[2][2][16][KROW];
    __shared__ float f1buf[BB][F1_DIM];

    const int u  = threadIdx.x;      // 0..511
    const int w  = u >> 6;           // wave 0..7
    const int l  = u & 63;
    const int c  = l & 15;           // n-col within tile / m-row for A-read
    const int hk = l >> 4;           // k-quarter; = batch in cell phase
    const int b0 = blockIdx.x * BB;

    // permuted N mapping: wave w tileA col c -> gate (c>>3),   unit 8w+(c&7)
    //                            tileB col c -> gate 2+(c>>3), unit 8w+(c&7)
    const int uu = 8 * w + (c & 7);
    const int r0 = ((c >> 3) + 0) * H_DIM + uu;   // global W row, tile A
    const int r1 = ((c >> 3) + 2) * H_DIM + uu;   // global W row, tile B

    // ---- weight fragments (resident): x-ktiles 0,1 / h-ktiles 2,3 ----
#define LW(nm, ktg, row) short8 nm##h, nm##l; \
    load_wfrag(W_ih, W_hh, ktg, row, hk, nm##h, nm##l);
    LW(wx0a, 0, r0) LW(wx1a, 1, r0) LW(wh0a, 2, r0) LW(wh1a, 3, r0)
    LW(wx0b, 0, r1) LW(wx1b, 1, r1) LW(wh0b, 2, r1) LW(wh1b, 3, r1)
#undef LW

    float bA = b_ih[r0] + b_hh[r0];
    float bB = b_ih[r1] + b_hh[r1];
    float cst = 0.0f;                // cell state: (batch hk, unit 8w+c), c<8

    // ---- x staging role: lanes c>=8, sv<200 -> (batch pb, input pi) ----
    const int  sv  = 32 * w + 8 * hk + (c & 7);
    const bool isp = (c >= 8) && (sv < 200);
    int pb = sv / I_DIM; if (pb > 3) pb = 3;
    const int pi  = sv - pb * I_DIM;
    const float* xp = x + ((size_t)(b0 + pb) * S_LEN) * I_DIM + pi;
    const int skt = pi >> 5, skc = pi & 31, srw = 4 * pb;

    // ---- zero all staging (h0=0, pad cols, unused rows) ----
    for (int i = u; i < 1280; i += 512) {
        ((unsigned*)Hhi)[i] = 0u; ((unsigned*)Hlo)[i] = 0u;
        ((unsigned*)Xhi)[i] = 0u; ((unsigned*)Xlo)[i] = 0u;
    }
    __syncthreads();
    if (isp) {                       // stage x(0)->X[0], x(1)->X[1]
        const float v0 = xp[0], v1 = xp[I_DIM];
        const unsigned short h0 = bf16_rne(v0);
        Xhi[0][skt][srw][skc] = h0;
        Xlo[0][skt][srw][skc] = bf16_rne(v0 - bf16f(h0));
        const unsigned short h1 = bf16_rne(v1);
        Xhi[1][skt][srw][skc] = h1;
        Xlo[1][skt][srw][skc] = bf16_rne(v1 - bf16f(h1));
    }
    __syncthreads();

#define MM3(ACC, AH, AL, WN) \
    ACC = __builtin_amdgcn_mfma_f32_16x16x32_bf16(AH, WN##h, ACC, 0, 0, 0); \
    ACC = __builtin_amdgcn_mfma_f32_16x16x32_bf16(AH, WN##l, ACC, 0, 0, 0); \
    ACC = __builtin_amdgcn_mfma_f32_16x16x32_bf16(AL, WN##h, ACC, 0, 0, 0);

    // ---- prologue: accA = bias + x(0)·W_ih from X[0] ----
    f32x4 aA0, aA1, aB0, aB1;
    aA0[0]=bA; aA0[1]=bA; aA0[2]=bA; aA0[3]=bA;
    aA1[0]=bB; aA1[1]=bB; aA1[2]=bB; aA1[3]=bB;
    aB0 = aA0; aB1 = aA1;            // init (overwritten in STEP)
    {
        const short8 xh0 = *(const short8*)&Xhi[0][0][c][hk * 8];
        const short8 xl0 = *(const short8*)&Xlo[0][0][c][hk * 8];
        const short8 xh1 = *(const short8*)&Xhi[0][1][c][hk * 8];
        const short8 xl1 = *(const short8*)&Xlo[0][1][c][hk * 8];
        MM3(aA0, xh0, xl0, wx0a) MM3(aA0, xh1, xl1, wx1a)
        MM3(aA1, xh0, xl0, wx0b) MM3(aA1, xh1, xl1, wx1b)
    }
    __syncthreads();                 // X[0] reads done before step-0 staging

    // ---- scan; ONE barrier per step; unrolled x2 for acc handoff ----
#define STEP(T, AP0, AP1, AN0, AN1, CUR, NXT) { \
    float xnext = 0.0f; \
    const bool dox = isp && ((T) + 2 < S_LEN); \
    if (dox) xnext = xp[(size_t)((T) + 2) * I_DIM];      /* issue early */ \
    const short8 ah0 = *(const short8*)&Hhi[CUR][0][c][hk * 8]; \
    const short8 al0 = *(const short8*)&Hlo[CUR][0][c][hk * 8]; \
    const short8 ah1 = *(const short8*)&Hhi[CUR][1][c][hk * 8]; \
    const short8 al1 = *(const short8*)&Hlo[CUR][1][c][hk * 8]; \
    const short8 xh0 = *(const short8*)&Xhi[NXT][0][c][hk * 8]; \
    const short8 xl0 = *(const short8*)&Xlo[NXT][0][c][hk * 8]; \
    const short8 xh1 = *(const short8*)&Xhi[NXT][1][c][hk * 8]; \
    const short8 xl1 = *(const short8*)&Xlo[NXT][1][c][hk * 8]; \
    MM3(AP0, ah0, al0, wh0a) MM3(AP0, ah1, al1, wh1a)    /* h-part */ \
    MM3(AP1, ah0, al0, wh0b) MM3(AP1, ah1, al1, wh1b) \
    const float v0 = AP0[0], v1 = AP1[0]; \
    const float y0 = __shfl_xor(v0, 8); \
    const float y1 = __shfl_xor(v1, 8); \
    AN0[0]=bA; AN0[1]=bA; AN0[2]=bA; AN0[3]=bA; \
    AN1[0]=bB; AN1[1]=bB; AN1[2]=bB; AN1[3]=bB; \
    MM3(AN0, xh0, xl0, wx0a) MM3(AN0, xh1, xl1, wx1a)    /* x-part t+1 */ \
    MM3(AN1, xh0, xl0, wx0b) MM3(AN1, xh1, xl1, wx1b) \
    const float gi = sigm(v0), gf = sigm(y0);            /* i,f  (c<8) */ \
    const float gg = tanh_fast(v1), go = sigm(y1);       /* g~,o (c<8) */ \
    if (c < 8) { \
        cst = fmaf(gf, cst, gi * gg); \
        const float hv = go * tanh_fast(cst); \
        const unsigned short hh = bf16_rne(hv); \
        Hhi[NXT][w >> 2][4 * hk][8 * (w & 3) + c] = hh; \
        Hlo[NXT][w >> 2][4 * hk][8 * (w & 3) + c] = bf16_rne(hv - bf16f(hh)); \
    } else if (dox) { \
        const unsigned short xh = bf16_rne(xnext); \
        Xhi[CUR][skt][srw][skc] = xh; \
        Xlo[CUR][skt][srw][skc] = bf16_rne(xnext - bf16f(xh)); \
    } \
    __syncthreads(); \
}

    for (int t = 0; t < S_LEN; t += 2) {
        asm volatile("" : "+v"(wx0ah), "+v"(wx0al), "+v"(wx1ah), "+v"(wx1al),
                          "+v"(wh0ah), "+v"(wh0al), "+v"(wh1ah), "+v"(wh1al));
        asm volatile("" : "+v"(wx0bh), "+v"(wx0bl), "+v"(wx1bh), "+v"(wx1bl),
                          "+v"(wh0bh), "+v"(wh0bl), "+v"(wh1bh), "+v"(wh1bl));
        asm volatile("" : "+v"(bA), "+v"(bB));
        STEP(t,     aA0, aA1, aB0, aB1, 0, 1)
        STEP(t + 1, aB0, aB1, aA0, aA1, 1, 0)
    }
#undef STEP
#undef MM3

    // ---- classifier head; h_last (hi+lo) in H[0], rows 4b ----
    if (u < BB * F1_DIM) {           // 128 threads
        const int b = u >> 5, f = u & 31;
        float acc = b1[f];
        #pragma unroll
        for (int j = 0; j < H_DIM; ++j) {
            const float hj = bf16f(Hhi[0][j >> 5][4 * b][j & 31])
                           + bf16f(Hlo[0][j >> 5][4 * b][j & 31]);
            acc = fmaf(hj, W1[f * H_DIM + j], acc);
        }
        f1buf[b][f] = fmaxf(acc, 0.0f);
    }
    __syncthreads();
    if (u < BB * C_DIM) {            // 8 threads
        const int b = u >> 1, cl = u & 1;
        float acc = b2[cl];
        #pragma unroll
        for (int f = 0; f < F1_DIM; ++f)
            acc = fmaf(f1buf[b][f], W2[cl * F1_DIM + f], acc);
        out[(size_t)(b0 + b) * C_DIM + cl] = acc;
    }
}

extern "C" void kernel_launch(void* const* d_in, const int* in_sizes, int n_in,
                              void* d_out, int out_size, void* d_ws, size_t ws_size,
                              hipStream_t stream) {
    const float* x   = (const float*)d_in[0];
    const float* Wih = (const float*)d_in[1];
    const float* Whh = (const float*)d_in[2];
    const float* bih = (const float*)d_in[3];
    const float* bhh = (const float*)d_in[4];
    const float* W1  = (const float*)d_in[5];
    const float* b1  = (const float*)d_in[6];
    const float* W2  = (const float*)d_in[7];
    const float* b2  = (const float*)d_in[8];
    float* out = (float*)d_out;

    hipLaunchKernelGGL(lstm_mfma, dim3(256), dim3(512), 0, stream,
                       x, Wih, Whh, bih, bhh, W1, b1, W2, b2, out);
}